// Round 8
// baseline (310.552 us; speedup 1.0000x reference)
//
#include <hip/hip_runtime.h>
#include <hip/hip_bf16.h>
#include <math.h>

#define NN 8192
#define NE 262144
#define EA (NE + NN)          // edges + self loops
#define SLOPE 0.2f
#define TH2 0.25f             // THRESH^2 : dist<0.5  <=>  d2<0.25

typedef __bf16 bf16x8 __attribute__((ext_vector_type(8)));
typedef float f32x16 __attribute__((ext_vector_type(16)));

__device__ __forceinline__ float lrelu(float x) { return x > 0.f ? x : SLOPE * x; }

// ---------------- K1: h = x@W1 (4 nodes/block), a_s/a_d head sums ----------------
__global__ void k_gemm1(const float* __restrict__ x, const float* __restrict__ W1,
                        const float* __restrict__ as1, const float* __restrict__ ad1,
                        float* __restrict__ h, float* __restrict__ a_s,
                        float* __restrict__ a_d) {
  const int nb = blockIdx.x << 2;
  const int t = threadIdx.x;
  __shared__ float xs[4][128];
  if (t < 128) ((float4*)xs)[t] = ((const float4*)(x + (size_t)nb * 128))[t];
  __syncthreads();
  float ac[4] = {0.f, 0.f, 0.f, 0.f};
  const float* wp = W1 + t;            // W1 [128][256]
#pragma unroll 4
  for (int k = 0; k < 128; ++k) {
    float wv = wp[(size_t)k << 8];
    ac[0] = fmaf(xs[0][k], wv, ac[0]);
    ac[1] = fmaf(xs[1][k], wv, ac[1]);
    ac[2] = fmaf(xs[2][k], wv, ac[2]);
    ac[3] = fmaf(xs[3][k], wv, ac[3]);
  }
  const float as1t = as1[t], ad1t = ad1[t];
#pragma unroll
  for (int i = 0; i < 4; ++i) {
    h[((size_t)(nb + i) << 8) + t] = ac[i];
    float av = ac[i] * as1t;
    float dv = ac[i] * ad1t;
#pragma unroll
    for (int m = 32; m >= 1; m >>= 1) {
      av += __shfl_xor(av, m, 64);
      dv += __shfl_xor(dv, m, 64);
    }
    if ((t & 63) == 0) {
      a_s[((nb + i) << 2) + (t >> 6)] = av;
      a_d[((nb + i) << 2) + (t >> 6)] = dv;
    }
  }
}

// ---------------- CSR build ----------------
__global__ void k_init(int* __restrict__ cnt) {
  int i = blockIdx.x * 256 + threadIdx.x;
  if (i < NN) cnt[i] = 1;               // self loop pre-counted
}
__global__ void k_hist(const int* __restrict__ ei, int* __restrict__ cnt) {
  int e = blockIdx.x * 256 + threadIdx.x;
  if (e < NE) atomicAdd(&cnt[ei[NE + e]], 1);
}
__global__ void k_scan(const int* __restrict__ cnt, int* __restrict__ start,
                       int* __restrict__ cursor) {
  __shared__ int s[1024];
  const int t = threadIdx.x;
  const int base = t << 3;
  int c[8];
  int run = 0;
#pragma unroll
  for (int i = 0; i < 8; ++i) { c[i] = cnt[base + i]; run += c[i]; }
  s[t] = run;
  __syncthreads();
  const int total = run;
  for (int off = 1; off < 1024; off <<= 1) {
    int v = (t >= off) ? s[t - off] : 0;
    __syncthreads();
    s[t] += v;
    __syncthreads();
  }
  int o = s[t] - total;                 // exclusive prefix
#pragma unroll
  for (int i = 0; i < 8; ++i) {
    start[base + i] = o;
    cursor[base + i] = o;
    o += c[i];
  }
}
__global__ void k_scatter(const int* __restrict__ ei, int* __restrict__ cursor,
                          int* __restrict__ eidx) {
  int e = blockIdx.x * 256 + threadIdx.x;
  if (e >= EA) return;
  int src, dst;
  if (e < NE) { src = ei[e]; dst = ei[NE + e]; } else { src = dst = e - NE; }
  int slot = atomicAdd(&cursor[dst], 1);
  eidx[slot] = src;
}

// ---------------- K_node: fused segment max + softmax + aggregate + post ----------------
// one block (256 threads) per dst node; thread t owns channel t; no f32 atomics.
__global__ void k_node(const int* __restrict__ start, const int* __restrict__ cnt,
                       const int* __restrict__ eidx, const float* __restrict__ a_s,
                       const float* __restrict__ a_d, const float* __restrict__ h,
                       const float* __restrict__ b1, const float* __restrict__ W2,
                       const float* __restrict__ as2, const float* __restrict__ ad2,
                       __bf16* __restrict__ fbf, float* __restrict__ sq,
                       float* __restrict__ thr_g, float* __restrict__ s2_g,
                       float* __restrict__ t2g, float* __restrict__ h2g) {
  const int n = blockIdx.x, t = threadIdx.x;
  __shared__ float red[16];             // [wave][head]
  __shared__ float hl[256];
  __shared__ float r2[4];
  __shared__ float h2l[16];
  const int st = start[n];
  const int deg = cnt[n];
  const float4 ad4 = *(const float4*)(a_d + ((size_t)n << 2));
  // pass1: per-head max over incoming edges
  float pm0 = -INFINITY, pm1 = -INFINITY, pm2 = -INFINITY, pm3 = -INFINITY;
  for (int e = t; e < deg; e += 256) {
    int src = eidx[st + e];
    float4 s4 = *(const float4*)(a_s + ((size_t)src << 2));
    pm0 = fmaxf(pm0, lrelu(s4.x + ad4.x));
    pm1 = fmaxf(pm1, lrelu(s4.y + ad4.y));
    pm2 = fmaxf(pm2, lrelu(s4.z + ad4.z));
    pm3 = fmaxf(pm3, lrelu(s4.w + ad4.w));
  }
#pragma unroll
  for (int m = 32; m >= 1; m >>= 1) {
    pm0 = fmaxf(pm0, __shfl_xor(pm0, m, 64));
    pm1 = fmaxf(pm1, __shfl_xor(pm1, m, 64));
    pm2 = fmaxf(pm2, __shfl_xor(pm2, m, 64));
    pm3 = fmaxf(pm3, __shfl_xor(pm3, m, 64));
  }
  if ((t & 63) == 0) {
    const int w = t >> 6;
    red[(w << 2) + 0] = pm0;
    red[(w << 2) + 1] = pm1;
    red[(w << 2) + 2] = pm2;
    red[(w << 2) + 3] = pm3;
  }
  __syncthreads();
  const int hd = t >> 6;                // head of this channel
  const float mhead = fmaxf(fmaxf(red[0 + hd], red[4 + hd]),
                            fmaxf(red[8 + hd], red[12 + hd]));
  const float adh = (hd == 0) ? ad4.x : (hd == 1) ? ad4.y : (hd == 2) ? ad4.z : ad4.w;
  // pass2: den and unnormalized aggregate, 4-way unrolled (independent chains)
  float dn0 = 0.f, dn1 = 0.f, dn2 = 0.f, dn3 = 0.f;
  float ac0 = 0.f, ac1 = 0.f, ac2 = 0.f, ac3 = 0.f;
  int e = 0;
  for (; e + 3 < deg; e += 4) {
    int s0 = eidx[st + e + 0], s1 = eidx[st + e + 1];
    int s2i = eidx[st + e + 2], s3 = eidx[st + e + 3];
    float z0 = __expf(lrelu(a_s[((size_t)s0 << 2) + hd] + adh) - mhead);
    float z1 = __expf(lrelu(a_s[((size_t)s1 << 2) + hd] + adh) - mhead);
    float z2 = __expf(lrelu(a_s[((size_t)s2i << 2) + hd] + adh) - mhead);
    float z3 = __expf(lrelu(a_s[((size_t)s3 << 2) + hd] + adh) - mhead);
    dn0 += z0; dn1 += z1; dn2 += z2; dn3 += z3;
    ac0 = fmaf(z0, h[((size_t)s0 << 8) + t], ac0);
    ac1 = fmaf(z1, h[((size_t)s1 << 8) + t], ac1);
    ac2 = fmaf(z2, h[((size_t)s2i << 8) + t], ac2);
    ac3 = fmaf(z3, h[((size_t)s3 << 8) + t], ac3);
  }
  for (; e < deg; ++e) {
    int s0 = eidx[st + e];
    float z0 = __expf(lrelu(a_s[((size_t)s0 << 2) + hd] + adh) - mhead);
    dn0 += z0;
    ac0 = fmaf(z0, h[((size_t)s0 << 8) + t], ac0);
  }
  float den = (dn0 + dn1) + (dn2 + dn3);
  float acc = (ac0 + ac1) + (ac2 + ac3);
  float v = acc / den + b1[t];
  float h1 = v > 0.f ? v : (__expf(v) - 1.f);        // elu
  fbf[((size_t)n << 8) + t] = (__bf16)h1;
  hl[t] = h1;
  float s = h1 * h1;
#pragma unroll
  for (int m = 32; m >= 1; m >>= 1) s += __shfl_xor(s, m, 64);
  if ((t & 63) == 0) r2[t >> 6] = s;
  __syncthreads();
  if (t < 16) {
    float a = 0.f;
#pragma unroll 8
    for (int c = 0; c < 256; ++c) a = fmaf(hl[c], W2[(c << 4) + t], a);
    h2g[((size_t)n << 4) + t] = a;
    h2l[t] = a;
  }
  __syncthreads();
  if (t == 0) {
    float sqv = r2[0] + r2[1] + r2[2] + r2[3];
    sq[n] = sqv;
    float ss = 0.f;
#pragma unroll
    for (int o = 0; o < 16; ++o) ss += h2l[o] * as2[o];
    thr_g[n] = (sqv - TH2) * 0.5f;
    s2_g[n] = ss;
  } else if (t == 1) {
    float tt = 0.f;
#pragma unroll
    for (int o = 0; o < 16; ++o) tt += h2l[o] * ad2[o];
    t2g[n] = tt;
  }
}

// ---------------- K_conv2: register-staged MFMA gram mask, 512 thr, 2 waves/SIMD ----------
// 256 blocks x 512 threads. Block owns 32 i (B-frags in VGPR). 8 waves each own a
// 32-j window per 256-j tile; A-frags loaded straight to VGPR (no LDS staging).
// Mask/softmax/o[16] lane-local; LDS used only for the final 16-partial merge.
__launch_bounds__(512, 2)
__global__ void k_conv2(const __bf16* __restrict__ fbf, const float* __restrict__ sq,
                        const float* __restrict__ thr_g, const float* __restrict__ s2_g,
                        const float* __restrict__ t2g, const float* __restrict__ h2g,
                        const float* __restrict__ b2, float* __restrict__ out) {
  __shared__ float mrg[512][18];                 // merge scratch (36 KB), used at end only

  const int t = threadIdx.x;
  const int lane = t & 63;
  const int w = t >> 6;                          // wave 0..7
  const int half = lane >> 5;
  const int rowA = lane & 31;
  const int i0 = blockIdx.x << 5;
  const int jw = w << 5;                         // wave's j-offset within 256-j tile

  // B-frags: fi row i0+rowA, k = kc*16 + half*8 + e  (one-time, 64 VGPR)
  bf16x8 bfr[16];
  {
    const char* fb = (const char*)fbf + (((size_t)(i0 + rowA)) << 9) + (half << 4);
#pragma unroll
    for (int kc = 0; kc < 16; ++kc) bfr[kc] = *(const bf16x8*)(fb + kc * 32);
  }
  const float sqi = sq[i0 + rowA];
  const float t2i = t2g[i0 + rowA];
  const float gb_i = 0.5f * sqi;                 // included iff G > gb_i + thr_j

  float m = -INFINITY, l = 0.f;
  float o[16];
#pragma unroll
  for (int c = 0; c < 16; ++c) o[c] = 0.f;

  for (int jt = 0; jt < 32; ++jt) {
    const int jbase = (jt << 8) + jw;            // this wave's 32-j window
    // ---- A-frags straight to VGPR: lane's row jbase+rowA, same k-slice as B ----
    bf16x8 afr[16];
    {
      const char* fr = (const char*)fbf + ((size_t)(jbase + rowA) << 9) + (half << 4);
#pragma unroll
      for (int kc = 0; kc < 16; ++kc) afr[kc] = *(const bf16x8*)(fr + kc * 32);
    }
    // ---- gram: G^T = Fj @ Fi^T, 16 mfma (2 chains) ----
    f32x16 acc0, acc1;
#pragma unroll
    for (int r = 0; r < 16; ++r) { acc0[r] = 0.f; acc1[r] = 0.f; }
#pragma unroll
    for (int kc = 0; kc < 16; kc += 2) {
      acc0 = __builtin_amdgcn_mfma_f32_32x32x16_bf16(afr[kc], bfr[kc], acc0, 0, 0, 0);
      acc1 = __builtin_amdgcn_mfma_f32_32x32x16_bf16(afr[kc + 1], bfr[kc + 1], acc1, 0, 0, 0);
    }

    // ---- per-lane thr/s2 for the 16 reg-j's: j = jbase + (r&3) + 8*(r>>2) + 4*half ----
    const float* tb = thr_g + jbase + (half << 2);
    const float* sb = s2_g + jbase + (half << 2);
    float4 thq[4], s2q[4];
#pragma unroll
    for (int q = 0; q < 4; ++q) {
      thq[q] = *(const float4*)(tb + (q << 3));
      s2q[q] = *(const float4*)(sb + (q << 3));
    }
    const float thv[16] = {thq[0].x, thq[0].y, thq[0].z, thq[0].w,
                           thq[1].x, thq[1].y, thq[1].z, thq[1].w,
                           thq[2].x, thq[2].y, thq[2].z, thq[2].w,
                           thq[3].x, thq[3].y, thq[3].z, thq[3].w};
    const float s2v[16] = {s2q[0].x, s2q[0].y, s2q[0].z, s2q[0].w,
                           s2q[1].x, s2q[1].y, s2q[1].z, s2q[1].w,
                           s2q[2].x, s2q[2].y, s2q[2].z, s2q[2].w,
                           s2q[3].x, s2q[3].y, s2q[3].z, s2q[3].w};

    unsigned msk = 0;
#pragma unroll
    for (int r = 0; r < 16; ++r) {
      float g = acc0[r] + acc1[r];
      if (g > gb_i + thv[r]) msk |= (1u << r);
    }

    if (msk) {                                   // rare: included neighbor(s)
      const int j0 = jbase + (half << 2);
#pragma unroll
      for (int r = 0; r < 16; ++r) {
        if (msk & (1u << r)) {
          float e = lrelu(s2v[r] + t2i);
          if (e > m) {
            float scl = __expf(m - e);
            l *= scl;
#pragma unroll
            for (int c = 0; c < 16; ++c) o[c] *= scl;
            m = e;
          }
          float p = __expf(e - m);
          l += p;
          int j = j0 + (r & 3) + ((r >> 2) << 3);
          const float4* hp = (const float4*)(h2g + ((size_t)j << 4));
          float4 q0 = hp[0], q1 = hp[1], q2 = hp[2], q3 = hp[3];
          o[0] += p * q0.x;  o[1] += p * q0.y;  o[2] += p * q0.z;  o[3] += p * q0.w;
          o[4] += p * q1.x;  o[5] += p * q1.y;  o[6] += p * q1.z;  o[7] += p * q1.w;
          o[8] += p * q2.x;  o[9] += p * q2.y;  o[10] += p * q2.z; o[11] += p * q2.w;
          o[12] += p * q3.x; o[13] += p * q3.y; o[14] += p * q3.z; o[15] += p * q3.w;
        }
      }
    }
  }

  // ---- merge 16 partials per i (8 waves x 2 halves) ----
  {
    float* mp = mrg[(w << 6) + (half << 5) + rowA];
    mp[0] = m;
    mp[1] = l;
#pragma unroll
    for (int c = 0; c < 16; ++c) mp[2 + c] = o[c];
  }
  __syncthreads();
  if (t < 32) {
    float M = -INFINITY;
#pragma unroll
    for (int s = 0; s < 16; ++s)
      M = fmaxf(M, mrg[((s >> 1) << 6) + ((s & 1) << 5) + t][0]);
    float L = 0.f, O[16];
#pragma unroll
    for (int c = 0; c < 16; ++c) O[c] = 0.f;
#pragma unroll
    for (int s = 0; s < 16; ++s) {
      const float* mp = mrg[((s >> 1) << 6) + ((s & 1) << 5) + t];
      float wt = __expf(mp[0] - M);              // 0 for empty partials
      L += mp[1] * wt;
#pragma unroll
      for (int c = 0; c < 16; ++c) O[c] += mp[2 + c] * wt;
    }
    float inv = 1.f / L;
    float v[16];
    float mx = -INFINITY;
#pragma unroll
    for (int c = 0; c < 16; ++c) {
      v[c] = O[c] * inv + b2[c];
      mx = fmaxf(mx, v[c]);
    }
    float se = 0.f;
#pragma unroll
    for (int c = 0; c < 16; ++c) se += __expf(v[c] - mx);
    float lse = mx + __logf(se);
    float4* op = (float4*)(out + ((size_t)(i0 + t) << 4));
#pragma unroll
    for (int gq = 0; gq < 4; ++gq)
      op[gq] = make_float4(v[gq * 4 + 0] - lse, v[gq * 4 + 1] - lse,
                           v[gq * 4 + 2] - lse, v[gq * 4 + 3] - lse);
  }
}

extern "C" void kernel_launch(void* const* d_in, const int* in_sizes, int n_in,
                              void* d_out, int out_size, void* d_ws, size_t ws_size,
                              hipStream_t stream) {
  const float* x   = (const float*)d_in[0];
  const int*   ei  = (const int*)d_in[1];
  const float* W1  = (const float*)d_in[2];
  const float* as1 = (const float*)d_in[3];
  const float* ad1 = (const float*)d_in[4];
  const float* b1  = (const float*)d_in[5];
  const float* W2  = (const float*)d_in[6];
  const float* as2 = (const float*)d_in[7];
  const float* ad2 = (const float*)d_in[8];
  const float* b2  = (const float*)d_in[9];
  float* out = (float*)d_out;

  float* p = (float*)d_ws;
  float* h     = p; p += (size_t)NN * 256;
  float* a_s   = p; p += (size_t)NN * 4;
  float* a_d   = p; p += (size_t)NN * 4;
  float* sq    = p; p += NN;
  float* t2    = p; p += NN;
  float* h2g   = p; p += (size_t)NN * 16;
  float* thr_g = p; p += NN;
  float* s2_g  = p; p += NN;
  __bf16* fbf  = (__bf16*)p; p += (size_t)NN * 128;   // NN*256 bf16
  int* cnt     = (int*)p; p += NN;
  int* startp  = (int*)p; p += NN;
  int* cursor  = (int*)p; p += NN;
  int* eidx    = (int*)p;

  k_init<<<NN / 256, 256, 0, stream>>>(cnt);
  k_hist<<<NE / 256, 256, 0, stream>>>(ei, cnt);
  k_gemm1<<<NN / 4, 256, 0, stream>>>(x, W1, as1, ad1, h, a_s, a_d);
  k_scan<<<1, 1024, 0, stream>>>(cnt, startp, cursor);
  k_scatter<<<(EA + 255) / 256, 256, 0, stream>>>(ei, cursor, eidx);
  k_node<<<NN, 256, 0, stream>>>(startp, cnt, eidx, a_s, a_d, h, b1, W2, as2, ad2,
                                 fbf, sq, thr_g, s2_g, t2, h2g);
  k_conv2<<<NN / 32, 512, 0, stream>>>(fbf, sq, thr_g, s2_g, t2, h2g, b2, out);
}

// Round 13
// 250.358 us; speedup vs baseline: 1.2404x; 1.2404x over previous
//
#include <hip/hip_runtime.h>
#include <hip/hip_bf16.h>
#include <math.h>

#define NN 8192
#define NE 262144
#define EA (NE + NN)          // edges + self loops
#define SLOPE 0.2f
#define TH2 0.25f             // THRESH^2 : dist<0.5  <=>  d2<0.25

typedef __bf16 bf16x8 __attribute__((ext_vector_type(8)));
typedef float f32x16 __attribute__((ext_vector_type(16)));

__device__ __forceinline__ float lrelu(float x) { return x > 0.f ? x : SLOPE * x; }

__device__ __forceinline__ void gl_lds16(const void* g, void* l) {
  __builtin_amdgcn_global_load_lds((const __attribute__((address_space(1))) void*)g,
                                   (__attribute__((address_space(3))) void*)l, 16, 0, 0);
}

// ---------------- K1: h = x@W1 (4 nodes/block), a_s/a_d head sums ----------------
__global__ void k_gemm1(const float* __restrict__ x, const float* __restrict__ W1,
                        const float* __restrict__ as1, const float* __restrict__ ad1,
                        float* __restrict__ h, float* __restrict__ a_s,
                        float* __restrict__ a_d) {
  const int nb = blockIdx.x << 2;
  const int t = threadIdx.x;
  __shared__ float xs[4][128];
  if (t < 128) ((float4*)xs)[t] = ((const float4*)(x + (size_t)nb * 128))[t];
  __syncthreads();
  float ac[4] = {0.f, 0.f, 0.f, 0.f};
  const float* wp = W1 + t;            // W1 [128][256]
#pragma unroll 4
  for (int k = 0; k < 128; ++k) {
    float wv = wp[(size_t)k << 8];
    ac[0] = fmaf(xs[0][k], wv, ac[0]);
    ac[1] = fmaf(xs[1][k], wv, ac[1]);
    ac[2] = fmaf(xs[2][k], wv, ac[2]);
    ac[3] = fmaf(xs[3][k], wv, ac[3]);
  }
  const float as1t = as1[t], ad1t = ad1[t];
#pragma unroll
  for (int i = 0; i < 4; ++i) {
    h[((size_t)(nb + i) << 8) + t] = ac[i];
    float av = ac[i] * as1t;
    float dv = ac[i] * ad1t;
#pragma unroll
    for (int m = 32; m >= 1; m >>= 1) {
      av += __shfl_xor(av, m, 64);
      dv += __shfl_xor(dv, m, 64);
    }
    if ((t & 63) == 0) {
      a_s[((nb + i) << 2) + (t >> 6)] = av;
      a_d[((nb + i) << 2) + (t >> 6)] = dv;
    }
  }
}

// ---------------- CSR build ----------------
__global__ void k_init(int* __restrict__ cnt) {
  int i = blockIdx.x * 256 + threadIdx.x;
  if (i < NN) cnt[i] = 1;               // self loop pre-counted
}
__global__ void k_hist(const int* __restrict__ ei, int* __restrict__ cnt) {
  int e = blockIdx.x * 256 + threadIdx.x;
  if (e < NE) atomicAdd(&cnt[ei[NE + e]], 1);
}
__global__ void k_scan(const int* __restrict__ cnt, int* __restrict__ start,
                       int* __restrict__ cursor) {
  __shared__ int s[1024];
  const int t = threadIdx.x;
  const int base = t << 3;
  int c[8];
  int run = 0;
#pragma unroll
  for (int i = 0; i < 8; ++i) { c[i] = cnt[base + i]; run += c[i]; }
  s[t] = run;
  __syncthreads();
  const int total = run;
  for (int off = 1; off < 1024; off <<= 1) {
    int v = (t >= off) ? s[t - off] : 0;
    __syncthreads();
    s[t] += v;
    __syncthreads();
  }
  int o = s[t] - total;                 // exclusive prefix
#pragma unroll
  for (int i = 0; i < 8; ++i) {
    start[base + i] = o;
    cursor[base + i] = o;
    o += c[i];
  }
}
__global__ void k_scatter(const int* __restrict__ ei, int* __restrict__ cursor,
                          int* __restrict__ eidx) {
  int e = blockIdx.x * 256 + threadIdx.x;
  if (e >= EA) return;
  int src, dst;
  if (e < NE) { src = ei[e]; dst = ei[NE + e]; } else { src = dst = e - NE; }
  int slot = atomicAdd(&cursor[dst], 1);
  eidx[slot] = src;
}

// ---------------- K_node: fused segment max + softmax + aggregate + post ----------------
__global__ void k_node(const int* __restrict__ start, const int* __restrict__ cnt,
                       const int* __restrict__ eidx, const float* __restrict__ a_s,
                       const float* __restrict__ a_d, const float* __restrict__ h,
                       const float* __restrict__ b1, const float* __restrict__ W2,
                       const float* __restrict__ as2, const float* __restrict__ ad2,
                       __bf16* __restrict__ fbf, float* __restrict__ sq,
                       float* __restrict__ thr_g, float* __restrict__ s2_g,
                       float* __restrict__ t2g, float* __restrict__ h2g) {
  const int n = blockIdx.x, t = threadIdx.x;
  __shared__ float red[16];             // [wave][head]
  __shared__ float hl[256];
  __shared__ float r2[4];
  __shared__ float h2l[16];
  const int st = start[n];
  const int deg = cnt[n];
  const float4 ad4 = *(const float4*)(a_d + ((size_t)n << 2));
  float pm0 = -INFINITY, pm1 = -INFINITY, pm2 = -INFINITY, pm3 = -INFINITY;
  for (int e = t; e < deg; e += 256) {
    int src = eidx[st + e];
    float4 s4 = *(const float4*)(a_s + ((size_t)src << 2));
    pm0 = fmaxf(pm0, lrelu(s4.x + ad4.x));
    pm1 = fmaxf(pm1, lrelu(s4.y + ad4.y));
    pm2 = fmaxf(pm2, lrelu(s4.z + ad4.z));
    pm3 = fmaxf(pm3, lrelu(s4.w + ad4.w));
  }
#pragma unroll
  for (int m = 32; m >= 1; m >>= 1) {
    pm0 = fmaxf(pm0, __shfl_xor(pm0, m, 64));
    pm1 = fmaxf(pm1, __shfl_xor(pm1, m, 64));
    pm2 = fmaxf(pm2, __shfl_xor(pm2, m, 64));
    pm3 = fmaxf(pm3, __shfl_xor(pm3, m, 64));
  }
  if ((t & 63) == 0) {
    const int w = t >> 6;
    red[(w << 2) + 0] = pm0;
    red[(w << 2) + 1] = pm1;
    red[(w << 2) + 2] = pm2;
    red[(w << 2) + 3] = pm3;
  }
  __syncthreads();
  const int hd = t >> 6;
  const float mhead = fmaxf(fmaxf(red[0 + hd], red[4 + hd]),
                            fmaxf(red[8 + hd], red[12 + hd]));
  const float adh = (hd == 0) ? ad4.x : (hd == 1) ? ad4.y : (hd == 2) ? ad4.z : ad4.w;
  float dn0 = 0.f, dn1 = 0.f, dn2 = 0.f, dn3 = 0.f;
  float ac0 = 0.f, ac1 = 0.f, ac2 = 0.f, ac3 = 0.f;
  int e = 0;
  for (; e + 3 < deg; e += 4) {
    int s0 = eidx[st + e + 0], s1 = eidx[st + e + 1];
    int s2i = eidx[st + e + 2], s3 = eidx[st + e + 3];
    float z0 = __expf(lrelu(a_s[((size_t)s0 << 2) + hd] + adh) - mhead);
    float z1 = __expf(lrelu(a_s[((size_t)s1 << 2) + hd] + adh) - mhead);
    float z2 = __expf(lrelu(a_s[((size_t)s2i << 2) + hd] + adh) - mhead);
    float z3 = __expf(lrelu(a_s[((size_t)s3 << 2) + hd] + adh) - mhead);
    dn0 += z0; dn1 += z1; dn2 += z2; dn3 += z3;
    ac0 = fmaf(z0, h[((size_t)s0 << 8) + t], ac0);
    ac1 = fmaf(z1, h[((size_t)s1 << 8) + t], ac1);
    ac2 = fmaf(z2, h[((size_t)s2i << 8) + t], ac2);
    ac3 = fmaf(z3, h[((size_t)s3 << 8) + t], ac3);
  }
  for (; e < deg; ++e) {
    int s0 = eidx[st + e];
    float z0 = __expf(lrelu(a_s[((size_t)s0 << 2) + hd] + adh) - mhead);
    dn0 += z0;
    ac0 = fmaf(z0, h[((size_t)s0 << 8) + t], ac0);
  }
  float den = (dn0 + dn1) + (dn2 + dn3);
  float acc = (ac0 + ac1) + (ac2 + ac3);
  float v = acc / den + b1[t];
  float h1 = v > 0.f ? v : (__expf(v) - 1.f);        // elu
  fbf[((size_t)n << 8) + t] = (__bf16)h1;
  hl[t] = h1;
  float s = h1 * h1;
#pragma unroll
  for (int m = 32; m >= 1; m >>= 1) s += __shfl_xor(s, m, 64);
  if ((t & 63) == 0) r2[t >> 6] = s;
  __syncthreads();
  if (t < 16) {
    float a = 0.f;
#pragma unroll 8
    for (int c = 0; c < 256; ++c) a = fmaf(hl[c], W2[(c << 4) + t], a);
    h2g[((size_t)n << 4) + t] = a;
    h2l[t] = a;
  }
  __syncthreads();
  if (t == 0) {
    float sqv = r2[0] + r2[1] + r2[2] + r2[3];
    sq[n] = sqv;
    float ss = 0.f;
#pragma unroll
    for (int o = 0; o < 16; ++o) ss += h2l[o] * as2[o];
    thr_g[n] = (sqv - TH2) * 0.5f;
    s2_g[n] = ss;
  } else if (t == 1) {
    float tt = 0.f;
#pragma unroll
    for (int o = 0; o < 16; ++o) tt += h2l[o] * ad2[o];
    t2g[n] = tt;
  }
}

// ---------------- K_conv2: shared-j tiles, 64 i-blocks x 8 j-slices, 2 blocks/CU ----------
// Block: 256 thr / 4 waves; wave w owns i-window i0+w*32 (bfr in VGPR). All waves share
// one 32-j staged tile (16KB, XOR-swizzled via pre-swizzled gl_lds source). Double-buffered;
// one __syncthreads per tile — barrier drain covered by the co-resident block.
// Emits per-block partials (m,l,o[16]) per i; k_merge combines 8 slices.
__launch_bounds__(256, 2)
__global__ void k_conv2(const __bf16* __restrict__ fbf, const float* __restrict__ sq,
                        const float* __restrict__ thr_g, const float* __restrict__ s2_g,
                        const float* __restrict__ t2g, const float* __restrict__ h2g,
                        float* __restrict__ part) {
  __shared__ __align__(16) char fj[2][16384];

  const int t = threadIdx.x;
  const int lane = t & 63;
  const int w = t >> 6;
  const int half = lane >> 5;
  const int lo = lane & 31;
  const int ib = blockIdx.x >> 3;
  const int js = blockIdx.x & 7;
  const int i0 = ib << 7;                        // 128 i per block
  const int iw = i0 + (w << 5);                  // this wave's 32-i window
  const size_t jslab = ((size_t)js << 19);       // js*1024 rows * 512 B

  // stage source offsets: thread t covers LDS linear (t*16 + p*4096);
  // local row r = p*8 + (t>>5); source col pre-swizzled (lo ^ r)&31 (m173 pattern)
  int soff[4];
#pragma unroll
  for (int p = 0; p < 4; ++p) {
    int r = (p << 3) + (t >> 5);
    soff[p] = (r << 9) + (((lo ^ r) & 31) << 4);
  }
  // swizzled read offsets within own row
  int colkey[16];
#pragma unroll
  for (int kc = 0; kc < 16; ++kc)
    colkey[kc] = ((((kc << 1) + half) ^ lo) & 31) << 4;

  // B-frags: fi row iw+lo, k-slice half*8 (64 VGPR, one-time)
  bf16x8 bfr[16];
  {
    const char* fb = (const char*)fbf + (((size_t)(iw + lo)) << 9) + (half << 4);
#pragma unroll
    for (int kc = 0; kc < 16; ++kc) bfr[kc] = *(const bf16x8*)(fb + kc * 32);
  }
  const float sqi = sq[iw + lo];
  const float t2i = t2g[iw + lo];
  const float gb_i = 0.5f * sqi;                 // included iff G > gb_i + thr_j

  float m = -INFINITY, l = 0.f;
  float o[16];
#pragma unroll
  for (int c = 0; c < 16; ++c) o[c] = 0.f;

#define STAGE(B, JT)                                                          \
  do {                                                                        \
    const char* gsrc = (const char*)fbf + jslab + ((size_t)(JT) << 14);       \
    _Pragma("unroll") for (int p = 0; p < 4; ++p)                             \
        gl_lds16(gsrc + soff[p], fj[B] + (p << 12) + (w << 10));              \
  } while (0)

  STAGE(0, 0);
  __syncthreads();

  for (int jt = 0; jt < 32; ++jt) {
    const int cur = jt & 1;
    if (jt < 31) STAGE(cur ^ 1, jt + 1);         // prefetch next tile (no wait)
    const int jbase = (js << 10) + (jt << 5);
    const char* rb = fj[cur] + (lo << 9);

    // ---- gram: G^T = Fj @ Fi^T, 16 mfma (2 chains) ----
    f32x16 acc0, acc1;
#pragma unroll
    for (int r = 0; r < 16; ++r) { acc0[r] = 0.f; acc1[r] = 0.f; }
#pragma unroll
    for (int kc = 0; kc < 16; kc += 2) {
      bf16x8 a0 = *(const bf16x8*)(rb + colkey[kc]);
      bf16x8 a1 = *(const bf16x8*)(rb + colkey[kc + 1]);
      acc0 = __builtin_amdgcn_mfma_f32_32x32x16_bf16(a0, bfr[kc], acc0, 0, 0, 0);
      acc1 = __builtin_amdgcn_mfma_f32_32x32x16_bf16(a1, bfr[kc + 1], acc1, 0, 0, 0);
    }

    // ---- per-lane thr/s2 (direct global float4, L2-hot) ----
    const float* tb = thr_g + jbase + (half << 2);
    const float* sb = s2_g + jbase + (half << 2);
    float4 thq[4], s2q[4];
#pragma unroll
    for (int q = 0; q < 4; ++q) {
      thq[q] = *(const float4*)(tb + (q << 3));
      s2q[q] = *(const float4*)(sb + (q << 3));
    }
    const float thv[16] = {thq[0].x, thq[0].y, thq[0].z, thq[0].w,
                           thq[1].x, thq[1].y, thq[1].z, thq[1].w,
                           thq[2].x, thq[2].y, thq[2].z, thq[2].w,
                           thq[3].x, thq[3].y, thq[3].z, thq[3].w};
    const float s2v[16] = {s2q[0].x, s2q[0].y, s2q[0].z, s2q[0].w,
                           s2q[1].x, s2q[1].y, s2q[1].z, s2q[1].w,
                           s2q[2].x, s2q[2].y, s2q[2].z, s2q[2].w,
                           s2q[3].x, s2q[3].y, s2q[3].z, s2q[3].w};

    unsigned msk = 0;
#pragma unroll
    for (int r = 0; r < 16; ++r) {
      float g = acc0[r] + acc1[r];
      if (g > gb_i + thv[r]) msk |= (1u << r);
    }

    if (msk) {                                   // rare: included neighbor(s)
      const int j0 = jbase + (half << 2);
#pragma unroll
      for (int r = 0; r < 16; ++r) {
        if (msk & (1u << r)) {
          float e = lrelu(s2v[r] + t2i);
          if (e > m) {
            float scl = __expf(m - e);
            l *= scl;
#pragma unroll
            for (int c = 0; c < 16; ++c) o[c] *= scl;
            m = e;
          }
          float p = __expf(e - m);
          l += p;
          int j = j0 + (r & 3) + ((r >> 2) << 3);
          const float4* hp = (const float4*)(h2g + ((size_t)j << 4));
          float4 q0 = hp[0], q1 = hp[1], q2 = hp[2], q3 = hp[3];
          o[0] += p * q0.x;  o[1] += p * q0.y;  o[2] += p * q0.z;  o[3] += p * q0.w;
          o[4] += p * q1.x;  o[5] += p * q1.y;  o[6] += p * q1.z;  o[7] += p * q1.w;
          o[8] += p * q2.x;  o[9] += p * q2.y;  o[10] += p * q2.z; o[11] += p * q2.w;
          o[12] += p * q3.x; o[13] += p * q3.y; o[14] += p * q3.z; o[15] += p * q3.w;
        }
      }
    }
    __syncthreads();                             // next-tile data ready; cur safe to overwrite
  }
#undef STAGE

  // ---- merge the two half-K partials within the wave (lane <-> lane+32) ----
  {
    float m2 = __shfl_xor(m, 32, 64);
    float l2 = __shfl_xor(l, 32, 64);
    float mn = fmaxf(m, m2);
    float w1 = (m == -INFINITY) ? 0.f : __expf(m - mn);
    float w2 = (m2 == -INFINITY) ? 0.f : __expf(m2 - mn);
    l = l * w1 + l2 * w2;
#pragma unroll
    for (int c = 0; c < 16; ++c) {
      float oc2 = __shfl_xor(o[c], 32, 64);
      o[c] = o[c] * w1 + oc2 * w2;
    }
    m = mn;
  }
  if (half == 0) {                               // SoA partials: part[field][js][NN]
    const int i = iw + lo;
    part[((size_t)(0 * 8 + js) << 13) + i] = m;
    part[((size_t)(1 * 8 + js) << 13) + i] = l;
#pragma unroll
    for (int c = 0; c < 16; ++c)
      part[((size_t)((2 + c) * 8 + js) << 13) + i] = o[c];
  }
}

// ---------------- K_merge: combine 8 slice-partials per node + bias + log_softmax --------
__global__ void k_merge(const float* __restrict__ part, const float* __restrict__ b2,
                        float* __restrict__ out) {
  const int i = blockIdx.x * 256 + threadIdx.x;
  float ms[8];
  float M = -INFINITY;
#pragma unroll
  for (int s = 0; s < 8; ++s) {
    ms[s] = part[((size_t)s << 13) + i];
    M = fmaxf(M, ms[s]);
  }
  // M is finite: the slice containing node i includes its self-loop (d2=0 < TH2)
  float wt[8];
  float L = 0.f;
#pragma unroll
  for (int s = 0; s < 8; ++s) {
    wt[s] = __expf(ms[s] - M);                   // 0 when ms=-inf
    L += part[((size_t)(8 + s) << 13) + i] * wt[s];
  }
  float O[16];
#pragma unroll
  for (int c = 0; c < 16; ++c) O[c] = 0.f;
#pragma unroll
  for (int s = 0; s < 8; ++s) {
#pragma unroll
    for (int c = 0; c < 16; ++c)
      O[c] += part[((size_t)((2 + c) * 8 + s) << 13) + i] * wt[s];
  }
  float inv = 1.f / L;
  float v[16];
  float mx = -INFINITY;
#pragma unroll
  for (int c = 0; c < 16; ++c) {
    v[c] = O[c] * inv + b2[c];
    mx = fmaxf(mx, v[c]);
  }
  float se = 0.f;
#pragma unroll
  for (int c = 0; c < 16; ++c) se += __expf(v[c] - mx);
  float lse = mx + __logf(se);
  float4* op = (float4*)(out + ((size_t)i << 4));
#pragma unroll
  for (int gq = 0; gq < 4; ++gq)
    op[gq] = make_float4(v[gq * 4 + 0] - lse, v[gq * 4 + 1] - lse,
                         v[gq * 4 + 2] - lse, v[gq * 4 + 3] - lse);
}

extern "C" void kernel_launch(void* const* d_in, const int* in_sizes, int n_in,
                              void* d_out, int out_size, void* d_ws, size_t ws_size,
                              hipStream_t stream) {
  const float* x   = (const float*)d_in[0];
  const int*   ei  = (const int*)d_in[1];
  const float* W1  = (const float*)d_in[2];
  const float* as1 = (const float*)d_in[3];
  const float* ad1 = (const float*)d_in[4];
  const float* b1  = (const float*)d_in[5];
  const float* W2  = (const float*)d_in[6];
  const float* as2 = (const float*)d_in[7];
  const float* ad2 = (const float*)d_in[8];
  const float* b2  = (const float*)d_in[9];
  float* out = (float*)d_out;

  float* p = (float*)d_ws;
  float* h     = p; p += (size_t)NN * 256;            // dead after k_node -> reused as part
  float* a_s   = p; p += (size_t)NN * 4;
  float* a_d   = p; p += (size_t)NN * 4;
  float* sq    = p; p += NN;
  float* t2    = p; p += NN;
  float* h2g   = p; p += (size_t)NN * 16;
  float* thr_g = p; p += NN;
  float* s2_g  = p; p += NN;
  __bf16* fbf  = (__bf16*)p; p += (size_t)NN * 128;   // NN*256 bf16
  int* cnt     = (int*)p; p += NN;
  int* startp  = (int*)p; p += NN;
  int* cursor  = (int*)p; p += NN;
  int* eidx    = (int*)p;
  float* part  = h;                                   // 18*8*NN floats = 4.5MB < 8MB

  k_init<<<NN / 256, 256, 0, stream>>>(cnt);
  k_hist<<<NE / 256, 256, 0, stream>>>(ei, cnt);
  k_gemm1<<<NN / 4, 256, 0, stream>>>(x, W1, as1, ad1, h, a_s, a_d);
  k_scan<<<1, 1024, 0, stream>>>(cnt, startp, cursor);
  k_scatter<<<(EA + 255) / 256, 256, 0, stream>>>(ei, cursor, eidx);
  k_node<<<NN, 256, 0, stream>>>(startp, cnt, eidx, a_s, a_d, h, b1, W2, as2, ad2,
                                 fbf, sq, thr_g, s2_g, t2, h2g);
  k_conv2<<<512, 256, 0, stream>>>(fbf, sq, thr_g, s2_g, t2, h2g, part);
  k_merge<<<NN / 256, 256, 0, stream>>>(part, b2, out);
}